// Round 3
// baseline (291.755 us; speedup 1.0000x reference)
//
#include <hip/hip_runtime.h>
#include <hip/hip_bf16.h>

#define TOK 8192
#define CDIM 768
#define NH 12
#define HD 64
#define QKV_N 2304

typedef __attribute__((ext_vector_type(8))) short bf16x8;
typedef __attribute__((ext_vector_type(4))) float f32x4;
typedef unsigned short ushort_t;

__device__ __forceinline__ ushort_t f2bf(float f) {
  unsigned u = __float_as_uint(f);
  u += 0x7fffu + ((u >> 16) & 1u);
  return (ushort_t)(u >> 16);
}

__device__ __forceinline__ f32x4 mfma16(bf16x8 a, bf16x8 b, f32x4 c) {
  return __builtin_amdgcn_mfma_f32_16x16x32_bf16(a, b, c, 0, 0, 0);
}

// XOR swizzle for 64-col (8-chunk) bf16 LDS rows
__device__ __forceinline__ int swz(int r) { return (r ^ (r >> 3)) & 7; }

__device__ __forceinline__ void gload16(const void* g, void* l) {
  __builtin_amdgcn_global_load_lds(
      (const __attribute__((address_space(1))) unsigned int*)g,
      (__attribute__((address_space(3))) unsigned int*)l, 16, 0, 0);
}

// ---------------- LayerNorm: 1 block per token, fp32 stats, bf16 out ----------
__global__ __launch_bounds__(256) void ln_kernel(const float* __restrict__ x,
                                                 const float* __restrict__ gamma,
                                                 const float* __restrict__ beta,
                                                 ushort_t* __restrict__ xn) {
  int t = blockIdx.x;
  const float* row = x + (size_t)t * CDIM;
  float v[3];
  float s = 0.f, s2 = 0.f;
#pragma unroll
  for (int i = 0; i < 3; i++) {
    v[i] = row[threadIdx.x + 256 * i];
    s += v[i];
    s2 += v[i] * v[i];
  }
#pragma unroll
  for (int off = 32; off; off >>= 1) {
    s += __shfl_xor(s, off);
    s2 += __shfl_xor(s2, off);
  }
  __shared__ float red[8];
  int wid = threadIdx.x >> 6, lane = threadIdx.x & 63;
  if (lane == 0) { red[wid] = s; red[wid + 4] = s2; }
  __syncthreads();
  s = red[0] + red[1] + red[2] + red[3];
  s2 = red[4] + red[5] + red[6] + red[7];
  float mu = s * (1.f / CDIM);
  float var = s2 * (1.f / CDIM) - mu * mu;
  float rstd = rsqrtf(var + 1e-5f);
  ushort_t* orow = xn + (size_t)t * CDIM;
#pragma unroll
  for (int i = 0; i < 3; i++) {
    int c = threadIdx.x + 256 * i;
    orow[c] = f2bf((v[i] - mu) * rstd * gamma[c] + beta[c]);
  }
}

// -------- Weight transpose to bf16: wt[z][n][k] = W_z[k][n] ------------------
__global__ __launch_bounds__(256) void wtrans_kernel(const float* __restrict__ Wq,
                                                     const float* __restrict__ Wk,
                                                     const float* __restrict__ Wv,
                                                     const float* __restrict__ Wo,
                                                     ushort_t* __restrict__ wt) {
  const float* W = (blockIdx.z == 0) ? Wq : (blockIdx.z == 1) ? Wk
                   : (blockIdx.z == 2) ? Wv : Wo;
  __shared__ float tile[32][33];
  int tr = blockIdx.y, tc = blockIdx.x;
  int tx = threadIdx.x, ty = threadIdx.y;
#pragma unroll
  for (int j = 0; j < 4; j++) {
    int k = tr * 32 + ty + j * 8;
    tile[ty + j * 8][tx] = W[(size_t)k * CDIM + tc * 32 + tx];
  }
  __syncthreads();
  ushort_t* o = wt + (size_t)blockIdx.z * CDIM * CDIM;
#pragma unroll
  for (int j = 0; j < 4; j++) {
    int n = tc * 32 + ty + j * 8;
    o[(size_t)n * CDIM + tr * 32 + tx] = f2bf(tile[tx][ty + j * 8]);
  }
}

// -------- GEMM (m97 structure): C[m][n] = sum_k A[m][k]*Bt[n][k] + epilogue --
// MODE 0: QKV fused (N=2304), bf16 out; Q third gets (+bias+pos)*0.125
// MODE 1: out-proj (N=768), fp32 out, +bias +fp32 residual
template <int MODE>
__global__ __launch_bounds__(256) void gemm_kernel(
    const ushort_t* __restrict__ A, const ushort_t* __restrict__ Bt,
    const float* __restrict__ b0, const float* __restrict__ b1,
    const float* __restrict__ b2, const float* __restrict__ extra,
    void* __restrict__ outp) {
  __shared__ __align__(16) ushort_t lds_a[128 * 64];
  __shared__ __align__(16) ushort_t lds_b[128 * 64];
  const int NB = (MODE == 0) ? 18 : 6;
  // XCD-chunked swizzle (nwg % 8 == 0 in both modes)
  int lin = blockIdx.y * NB + blockIdx.x;
  int nl = (lin & 7) * (NB * 8) + (lin >> 3);
  const int bn = nl % NB, bm = nl / NB;

  const int tid = threadIdx.x;
  const int lane = tid & 63, wid = tid >> 6;
  const int wr = wid >> 1, wc = wid & 1;
  const int l16 = lane & 15, lg = lane >> 4;
  f32x4 acc[4][4] = {};

  for (int k0 = 0; k0 < CDIM; k0 += 64) {
#pragma unroll
    for (int i = 0; i < 4; i++) {
      int slot = i * 256 + tid;           // 1024 chunks of 16B per tile
      int row = slot >> 3, c8 = (slot & 7) * 8;
      gload16(&A[(size_t)(bm * 128 + row) * CDIM + k0 + c8], &lds_a[slot * 8]);
      gload16(&Bt[(size_t)(bn * 128 + row) * CDIM + k0 + c8], &lds_b[slot * 8]);
    }
    __syncthreads();  // drains vmcnt: staged data visible
#pragma unroll
    for (int kk = 0; kk < 2; kk++) {
      bf16x8 af[4], bfr[4];
#pragma unroll
      for (int mi = 0; mi < 4; mi++)
        af[mi] = *reinterpret_cast<const bf16x8*>(
            &lds_a[(wr * 64 + mi * 16 + l16) * 64 + kk * 32 + lg * 8]);
#pragma unroll
      for (int ni = 0; ni < 4; ni++)
        bfr[ni] = *reinterpret_cast<const bf16x8*>(
            &lds_b[(wc * 64 + ni * 16 + l16) * 64 + kk * 32 + lg * 8]);
#pragma unroll
      for (int mi = 0; mi < 4; mi++)
#pragma unroll
        for (int ni = 0; ni < 4; ni++)
          acc[mi][ni] = mfma16(af[mi], bfr[ni], acc[mi][ni]);
    }
    __syncthreads();  // all reads done before next stage overwrites
  }

#pragma unroll
  for (int mi = 0; mi < 4; mi++)
#pragma unroll
    for (int ni = 0; ni < 4; ni++)
#pragma unroll
      for (int r = 0; r < 4; r++) {
        int grow = bm * 128 + wr * 64 + mi * 16 + 4 * lg + r;
        int gcol = bn * 128 + wc * 64 + ni * 16 + l16;
        float v = acc[mi][ni][r];
        if (MODE == 0) {
          if (gcol < 768) {
            // Q: add bias + pos_embed, pre-scale by 1/sqrt(64) (exact in bf16)
            v = (v + b0[gcol] + extra[(size_t)grow * CDIM + gcol]) * 0.125f;
          } else if (gcol < 1536) {
            v += b1[gcol - 768];
          } else {
            v += b2[gcol - 1536];
          }
          ((ushort_t*)outp)[(size_t)grow * QKV_N + gcol] = f2bf(v);
        } else {
          v += b0[gcol] + extra[(size_t)grow * CDIM + gcol];
          ((float*)outp)[(size_t)grow * CDIM + gcol] = v;
        }
      }
}

// -------- Flash attention v3 ------------------------------------------------
// Structure of v2 (staged K via global_load_lds, vectorized V transpose,
// double-buffered K/V, XCD swizzle) + round-1-PROVEN softmax numerics
// (true online max, fp32 psum via shuffles, scalar f2bf P-writes).
__global__ __launch_bounds__(256) void attn_kernel(const ushort_t* __restrict__ QKV,
                                                   ushort_t* __restrict__ O) {
  // XCD-chunked swizzle: each XCD owns one batch b (K/V hot set ~3MB -> L2)
  int lin = (blockIdx.z * NH + blockIdx.y) * 8 + blockIdx.x;
  int nl = (lin & 7) * 96 + (lin >> 3);
  const int qt = nl & 7;
  const int h = (nl >> 3) % NH;
  const int b = nl / 96;

  const int tid = threadIdx.x, lane = tid & 63, w = tid >> 6;
  const int l16 = lane & 15, lg = lane >> 4;
  const int tb = b * 1024 + qt * 128;
  const int co_q = h * HD, co_k = CDIM + h * HD, co_v = 2 * CDIM + h * HD;

  __shared__ __align__(16) ushort_t k_lds[2][64 * 64];
  __shared__ __align__(16) ushort_t vt_lds[2][64 * 64];
  __shared__ __align__(16) ushort_t p_lds[128 * 64];

  // Q fragments (already scaled by 1/8 in the QKV-GEMM epilogue)
  bf16x8 qf[2][2];
#pragma unroll
  for (int mi = 0; mi < 2; mi++)
#pragma unroll
    for (int ds = 0; ds < 2; ds++)
      qf[mi][ds] = *reinterpret_cast<const bf16x8*>(
          &QKV[(size_t)(tb + w * 32 + mi * 16 + l16) * QKV_N + co_q + ds * 32 + 8 * lg]);

  float mrow[2][4], lrow[2][4];
  f32x4 oacc[2][4] = {};
#pragma unroll
  for (int mi = 0; mi < 2; mi++)
#pragma unroll
    for (int r = 0; r < 4; r++) { mrow[mi][r] = -1e30f; lrow[mi][r] = 0.f; }

  uint4 vr0, vr1;
  const int ch0 = tid, ch1 = tid + 256;  // V chunk ids (512 chunks of 8 elems)
  const int kvA = ch0 >> 3, dA = (ch0 & 7) * 8;
  const int kvB = ch1 >> 3, dB = (ch1 & 7) * 8;

  auto stage_k = [&](int buf, int kt) {
    const int kv0 = kt * 64;
#pragma unroll
    for (int i = 0; i < 2; i++) {
      int slot = i * 256 + tid;  // 512 chunks of 16B
      int r = slot >> 3, j = slot & 7;
      int c = ((j ^ swz(r)) & 7) * 8;  // pre-swizzled source column
      gload16(&QKV[(size_t)(b * 1024 + kv0 + r) * QKV_N + co_k + c],
              &k_lds[buf][slot * 8]);
    }
  };
  auto load_v = [&](int kt) {
    const int kv0 = kt * 64;
    vr0 = *reinterpret_cast<const uint4*>(
        &QKV[(size_t)(b * 1024 + kv0 + kvA) * QKV_N + co_v + dA]);
    vr1 = *reinterpret_cast<const uint4*>(
        &QKV[(size_t)(b * 1024 + kv0 + kvB) * QKV_N + co_v + dB]);
  };
  auto write_v = [&](int buf) {
#pragma unroll
    for (int i = 0; i < 2; i++) {
      const uint4& vr = i ? vr1 : vr0;
      int kv = i ? kvB : kvA, d0 = i ? dB : dA;
      const ushort_t* e = reinterpret_cast<const ushort_t*>(&vr);
#pragma unroll
      for (int u = 0; u < 8; u++) {
        int d = d0 + u;
        int pos = ((kv >> 3) ^ swz(d)) & 7;
        vt_lds[buf][d * 64 + pos * 8 + (kv & 7)] = e[u];
      }
    }
  };

  // prologue
  stage_k(0, 0);
  load_v(0);
  write_v(0);
  __syncthreads();

  for (int kt = 0; kt < 16; kt++) {
    const int cur = kt & 1, nxt = cur ^ 1;
    if (kt < 15) { stage_k(nxt, kt + 1); load_v(kt + 1); }

    // S = Q K^T (scale folded into Q)
    f32x4 sacc[2][4] = {};
#pragma unroll
    for (int ds = 0; ds < 2; ds++) {
      bf16x8 kf[4];
#pragma unroll
      for (int ni = 0; ni < 4; ni++) {
        int rr = ni * 16 + l16;
        int pos = ((ds * 4 + lg) ^ swz(rr)) & 7;
        kf[ni] = *reinterpret_cast<const bf16x8*>(&k_lds[cur][rr * 64 + pos * 8]);
      }
#pragma unroll
      for (int mi = 0; mi < 2; mi++)
#pragma unroll
        for (int ni = 0; ni < 4; ni++)
          sacc[mi][ni] = mfma16(qf[mi][ds], kf[ni], sacc[mi][ni]);
    }

    // online softmax — round-1 proven path (true max, fp32 psum)
#pragma unroll
    for (int mi = 0; mi < 2; mi++)
#pragma unroll
      for (int r = 0; r < 4; r++) {
        float tm = fmaxf(fmaxf(sacc[mi][0][r], sacc[mi][1][r]),
                         fmaxf(sacc[mi][2][r], sacc[mi][3][r]));
#pragma unroll
        for (int off = 1; off < 16; off <<= 1) tm = fmaxf(tm, __shfl_xor(tm, off));
        float newm = fmaxf(mrow[mi][r], tm);
        float corr = __expf(mrow[mi][r] - newm);
        mrow[mi][r] = newm;
        float psum = 0.f;
#pragma unroll
        for (int ni = 0; ni < 4; ni++) {
          float p = __expf(sacc[mi][ni][r] - newm);
          sacc[mi][ni][r] = p;
          psum += p;
        }
#pragma unroll
        for (int off = 1; off < 16; off <<= 1) psum += __shfl_xor(psum, off);
        lrow[mi][r] = lrow[mi][r] * corr + psum;
#pragma unroll
        for (int ni = 0; ni < 4; ni++) oacc[mi][ni][r] *= corr;
      }

    // P -> LDS (bf16 f2bf, swizzled chunks); wave-private rows
#pragma unroll
    for (int mi = 0; mi < 2; mi++)
#pragma unroll
      for (int ni = 0; ni < 4; ni++)
#pragma unroll
        for (int r = 0; r < 4; r++) {
          int prow = w * 32 + mi * 16 + 4 * lg + r;
          int chunk = ni * 2 + (l16 >> 3);
          int pos = (chunk ^ swz(prow)) & 7;
          p_lds[prow * 64 + pos * 8 + (l16 & 7)] = f2bf(sacc[mi][ni][r]);
        }

    // O += P @ V
#pragma unroll
    for (int ks = 0; ks < 2; ks++) {
      bf16x8 pa[2], vb[4];
#pragma unroll
      for (int mi = 0; mi < 2; mi++) {
        int prow = w * 32 + mi * 16 + l16;
        int pos = ((ks * 4 + lg) ^ swz(prow)) & 7;
        pa[mi] = *reinterpret_cast<const bf16x8*>(&p_lds[prow * 64 + pos * 8]);
      }
#pragma unroll
      for (int ni = 0; ni < 4; ni++) {
        int d = ni * 16 + l16;
        int pos = ((ks * 4 + lg) ^ swz(d)) & 7;
        vb[ni] = *reinterpret_cast<const bf16x8*>(&vt_lds[cur][d * 64 + pos * 8]);
      }
#pragma unroll
      for (int mi = 0; mi < 2; mi++)
#pragma unroll
        for (int ni = 0; ni < 4; ni++)
          oacc[mi][ni] = mfma16(pa[mi], vb[ni], oacc[mi][ni]);
    }

    if (kt < 15) write_v(nxt);
    __syncthreads();
  }

#pragma unroll
  for (int mi = 0; mi < 2; mi++)
#pragma unroll
    for (int ni = 0; ni < 4; ni++)
#pragma unroll
      for (int r = 0; r < 4; r++) {
        int grow = tb + w * 32 + mi * 16 + 4 * lg + r;
        int gcol = h * HD + ni * 16 + l16;
        O[(size_t)grow * CDIM + gcol] = f2bf(oacc[mi][ni][r] / lrow[mi][r]);
      }
}

extern "C" void kernel_launch(void* const* d_in, const int* in_sizes, int n_in,
                              void* d_out, int out_size, void* d_ws, size_t ws_size,
                              hipStream_t stream) {
  const float* x     = (const float*)d_in[0];
  const float* pos   = (const float*)d_in[1];
  const float* gamma = (const float*)d_in[2];
  const float* beta  = (const float*)d_in[3];
  const float* Wq    = (const float*)d_in[4];
  const float* bq    = (const float*)d_in[5];
  const float* Wk    = (const float*)d_in[6];
  const float* bk    = (const float*)d_in[7];
  const float* Wv    = (const float*)d_in[8];
  const float* bv    = (const float*)d_in[9];
  const float* Wo    = (const float*)d_in[10];
  const float* bo    = (const float*)d_in[11];
  float* out = (float*)d_out;

  ushort_t* xn   = (ushort_t*)d_ws;                    // 8192*768
  ushort_t* wt   = xn + (size_t)TOK * CDIM;            // 3072*768 (q,k,v,o transposed)
  ushort_t* qkv  = wt + (size_t)3072 * CDIM;           // 8192*2304
  ushort_t* aout = qkv + (size_t)TOK * QKV_N;          // 8192*768

  ln_kernel<<<TOK, 256, 0, stream>>>(x, gamma, beta, xn);
  wtrans_kernel<<<dim3(24, 24, 4), dim3(32, 8), 0, stream>>>(Wq, Wk, Wv, Wo, wt);
  gemm_kernel<0><<<dim3(18, 64), 256, 0, stream>>>(xn, wt, bq, bk, bv, pos, qkv);
  attn_kernel<<<dim3(8, NH, 8), 256, 0, stream>>>(qkv, aout);
  gemm_kernel<1><<<dim3(6, 64), 256, 0, stream>>>(aout, wt + (size_t)QKV_N * CDIM,
                                                  bo, nullptr, nullptr, x, out);
}

// Round 4
// 237.982 us; speedup vs baseline: 1.2260x; 1.2260x over previous
//
#include <hip/hip_runtime.h>
#include <hip/hip_bf16.h>

#define TOK 8192
#define CDIM 768
#define NH 12
#define HD 64
#define QKV_N 2304

typedef __attribute__((ext_vector_type(8))) short bf16x8;
typedef __attribute__((ext_vector_type(4))) float f32x4;
typedef unsigned short ushort_t;

__device__ __forceinline__ ushort_t f2bf(float f) {
  unsigned u = __float_as_uint(f);
  u += 0x7fffu + ((u >> 16) & 1u);
  return (ushort_t)(u >> 16);
}

__device__ __forceinline__ f32x4 mfma16(bf16x8 a, bf16x8 b, f32x4 c) {
  return __builtin_amdgcn_mfma_f32_16x16x32_bf16(a, b, c, 0, 0, 0);
}

// XOR swizzle for 64-col (8-chunk) bf16 LDS rows
__device__ __forceinline__ int swz(int r) { return (r ^ (r >> 3)) & 7; }

__device__ __forceinline__ void gload16(const void* g, void* l) {
  __builtin_amdgcn_global_load_lds(
      (const __attribute__((address_space(1))) unsigned int*)g,
      (__attribute__((address_space(3))) unsigned int*)l, 16, 0, 0);
}

// ---------------- LayerNorm: 1 block per token, fp32 stats, bf16 out ----------
__global__ __launch_bounds__(256) void ln_kernel(const float* __restrict__ x,
                                                 const float* __restrict__ gamma,
                                                 const float* __restrict__ beta,
                                                 ushort_t* __restrict__ xn) {
  int t = blockIdx.x;
  const float* row = x + (size_t)t * CDIM;
  float v[3];
  float s = 0.f, s2 = 0.f;
#pragma unroll
  for (int i = 0; i < 3; i++) {
    v[i] = row[threadIdx.x + 256 * i];
    s += v[i];
    s2 += v[i] * v[i];
  }
#pragma unroll
  for (int off = 32; off; off >>= 1) {
    s += __shfl_xor(s, off);
    s2 += __shfl_xor(s2, off);
  }
  __shared__ float red[8];
  int wid = threadIdx.x >> 6, lane = threadIdx.x & 63;
  if (lane == 0) { red[wid] = s; red[wid + 4] = s2; }
  __syncthreads();
  s = red[0] + red[1] + red[2] + red[3];
  s2 = red[4] + red[5] + red[6] + red[7];
  float mu = s * (1.f / CDIM);
  float var = s2 * (1.f / CDIM) - mu * mu;
  float rstd = rsqrtf(var + 1e-5f);
  ushort_t* orow = xn + (size_t)t * CDIM;
#pragma unroll
  for (int i = 0; i < 3; i++) {
    int c = threadIdx.x + 256 * i;
    orow[c] = f2bf((v[i] - mu) * rstd * gamma[c] + beta[c]);
  }
}

// -------- Weight transpose to bf16: wt[z][n][k] = W_z[k][n] ------------------
__global__ __launch_bounds__(256) void wtrans_kernel(const float* __restrict__ Wq,
                                                     const float* __restrict__ Wk,
                                                     const float* __restrict__ Wv,
                                                     const float* __restrict__ Wo,
                                                     ushort_t* __restrict__ wt) {
  const float* W = (blockIdx.z == 0) ? Wq : (blockIdx.z == 1) ? Wk
                   : (blockIdx.z == 2) ? Wv : Wo;
  __shared__ float tile[32][33];
  int tr = blockIdx.y, tc = blockIdx.x;
  int tx = threadIdx.x, ty = threadIdx.y;
#pragma unroll
  for (int j = 0; j < 4; j++) {
    int k = tr * 32 + ty + j * 8;
    tile[ty + j * 8][tx] = W[(size_t)k * CDIM + tc * 32 + tx];
  }
  __syncthreads();
  ushort_t* o = wt + (size_t)blockIdx.z * CDIM * CDIM;
#pragma unroll
  for (int j = 0; j < 4; j++) {
    int n = tc * 32 + ty + j * 8;
    o[(size_t)n * CDIM + tr * 32 + tx] = f2bf(tile[tx][ty + j * 8]);
  }
}

// -------- GEMM (m97 structure): C[m][n] = sum_k A[m][k]*Bt[n][k] + epilogue --
// MODE 0: QKV fused (N=2304), bf16 out; Q third gets (+bias+pos)*0.125
// MODE 1: out-proj (N=768), fp32 out, +bias +fp32 residual
template <int MODE>
__global__ __launch_bounds__(256) void gemm_kernel(
    const ushort_t* __restrict__ A, const ushort_t* __restrict__ Bt,
    const float* __restrict__ b0, const float* __restrict__ b1,
    const float* __restrict__ b2, const float* __restrict__ extra,
    void* __restrict__ outp) {
  __shared__ __align__(16) ushort_t lds_a[128 * 64];
  __shared__ __align__(16) ushort_t lds_b[128 * 64];
  const int NB = (MODE == 0) ? 18 : 6;
  // XCD-chunked swizzle (nwg % 8 == 0 in both modes)
  int lin = blockIdx.y * NB + blockIdx.x;
  int nl = (lin & 7) * (NB * 8) + (lin >> 3);
  const int bn = nl % NB, bm = nl / NB;

  const int tid = threadIdx.x;
  const int lane = tid & 63, wid = tid >> 6;
  const int wr = wid >> 1, wc = wid & 1;
  const int l16 = lane & 15, lg = lane >> 4;
  f32x4 acc[4][4] = {};

  for (int k0 = 0; k0 < CDIM; k0 += 64) {
#pragma unroll
    for (int i = 0; i < 4; i++) {
      int slot = i * 256 + tid;           // 1024 chunks of 16B per tile
      int row = slot >> 3, c8 = (slot & 7) * 8;
      gload16(&A[(size_t)(bm * 128 + row) * CDIM + k0 + c8], &lds_a[slot * 8]);
      gload16(&Bt[(size_t)(bn * 128 + row) * CDIM + k0 + c8], &lds_b[slot * 8]);
    }
    __syncthreads();  // drains vmcnt: staged data visible
#pragma unroll
    for (int kk = 0; kk < 2; kk++) {
      bf16x8 af[4], bfr[4];
#pragma unroll
      for (int mi = 0; mi < 4; mi++)
        af[mi] = *reinterpret_cast<const bf16x8*>(
            &lds_a[(wr * 64 + mi * 16 + l16) * 64 + kk * 32 + lg * 8]);
#pragma unroll
      for (int ni = 0; ni < 4; ni++)
        bfr[ni] = *reinterpret_cast<const bf16x8*>(
            &lds_b[(wc * 64 + ni * 16 + l16) * 64 + kk * 32 + lg * 8]);
#pragma unroll
      for (int mi = 0; mi < 4; mi++)
#pragma unroll
        for (int ni = 0; ni < 4; ni++)
          acc[mi][ni] = mfma16(af[mi], bfr[ni], acc[mi][ni]);
    }
    __syncthreads();  // all reads done before next stage overwrites
  }

#pragma unroll
  for (int mi = 0; mi < 4; mi++)
#pragma unroll
    for (int ni = 0; ni < 4; ni++)
#pragma unroll
      for (int r = 0; r < 4; r++) {
        int grow = bm * 128 + wr * 64 + mi * 16 + 4 * lg + r;
        int gcol = bn * 128 + wc * 64 + ni * 16 + l16;
        float v = acc[mi][ni][r];
        if (MODE == 0) {
          if (gcol < 768) {
            // Q: add bias + pos_embed, pre-scale by 1/sqrt(64) (exact in bf16)
            v = (v + b0[gcol] + extra[(size_t)grow * CDIM + gcol]) * 0.125f;
          } else if (gcol < 1536) {
            v += b1[gcol - 768];
          } else {
            v += b2[gcol - 1536];
          }
          ((ushort_t*)outp)[(size_t)grow * QKV_N + gcol] = f2bf(v);
        } else {
          v += b0[gcol] + extra[(size_t)grow * CDIM + gcol];
          ((float*)outp)[(size_t)grow * CDIM + gcol] = v;
        }
      }
}

// -------- Flash attention v4: swapped QK^T, lane-local softmax ---------------
// QBLK=64 (grid 1536), 4 waves x 16 q-rows. S^T = mfma(K,Q): each lane owns
// one q-row (col=l16), 16 kv values in regs -> softmax is in-lane + 2 shfl_xor.
// K direct from global (L2-resident, no barrier). V^T double-buffered in LDS
// (one barrier/iter). P through wave-private swizzled LDS (no barrier).
__global__ __launch_bounds__(256) void attn_kernel(const ushort_t* __restrict__ QKV,
                                                   ushort_t* __restrict__ O) {
  // XCD-chunked swizzle over 1536 = 8 x 192: each XCD owns one batch b
  int lin = (blockIdx.z * NH + blockIdx.y) * 16 + blockIdx.x;
  int nl = (lin & 7) * 192 + (lin >> 3);
  const int qt = nl & 15;
  const int h = (nl >> 4) % NH;
  const int b = nl / 192;

  const int tid = threadIdx.x, lane = tid & 63, w = tid >> 6;
  const int l16 = lane & 15, lg = lane >> 4;
  const int tb = b * 1024 + qt * 64;
  const int co_q = h * HD, co_k = CDIM + h * HD, co_v = 2 * CDIM + h * HD;

  __shared__ __align__(16) ushort_t vt_lds[2][64 * 64];
  __shared__ __align__(16) ushort_t p_lds[64 * 64];

  // Q as B-fragment: rows q = w*16 + l16 (scale 1/8 folded in by QKV-GEMM)
  bf16x8 qf[2];
#pragma unroll
  for (int ds = 0; ds < 2; ds++)
    qf[ds] = *reinterpret_cast<const bf16x8*>(
        &QKV[(size_t)(tb + w * 16 + l16) * QKV_N + co_q + ds * 32 + 8 * lg]);

  const int myq = w * 16 + l16;       // this lane's softmax row (block-local)
  float m_sm = -1e30f, l_sm = 0.f;    // per-lane row stats (row = myq)
  float m_acc[4];                      // same stats in oacc-row layout (4*lg+r)
#pragma unroll
  for (int r = 0; r < 4; r++) m_acc[r] = -1e30f;
  f32x4 oacc[4] = {};

  uint4 vr0, vr1;
  const int kvA = tid >> 3, dA = (tid & 7) * 8;
  const int kvB = (tid + 256) >> 3, dB = ((tid + 256) & 7) * 8;

  auto load_v = [&](int kt) {
    const int kv0 = kt * 64;
    vr0 = *reinterpret_cast<const uint4*>(
        &QKV[(size_t)(b * 1024 + kv0 + kvA) * QKV_N + co_v + dA]);
    vr1 = *reinterpret_cast<const uint4*>(
        &QKV[(size_t)(b * 1024 + kv0 + kvB) * QKV_N + co_v + dB]);
  };
  auto write_v = [&](int buf) {
#pragma unroll
    for (int i = 0; i < 2; i++) {
      const uint4& vr = i ? vr1 : vr0;
      int kv = i ? kvB : kvA, d0 = i ? dB : dA;
      const ushort_t* e = reinterpret_cast<const ushort_t*>(&vr);
#pragma unroll
      for (int u = 0; u < 8; u++) {
        int d = d0 + u;
        int pos = ((kv >> 3) ^ swz(d)) & 7;
        vt_lds[buf][d * 64 + pos * 8 + (kv & 7)] = e[u];
      }
    }
  };

  // prologue
  load_v(0);
  write_v(0);
  __syncthreads();

  for (int kt = 0; kt < 16; kt++) {
    const int cur = kt & 1, nxt = cur ^ 1;
    if (kt < 15) load_v(kt + 1);

    // K as A-fragment: rows kv = ni*16 + l16 (direct from global, L2-hot)
    bf16x8 kf[2][4];
#pragma unroll
    for (int ds = 0; ds < 2; ds++)
#pragma unroll
      for (int ni = 0; ni < 4; ni++)
        kf[ds][ni] = *reinterpret_cast<const bf16x8*>(
            &QKV[(size_t)(b * 1024 + kt * 64 + ni * 16 + l16) * QKV_N +
                 co_k + ds * 32 + 8 * lg]);

    // S^T = K Q^T : lane holds col q=l16, rows kv = ni*16 + 4*lg + r
    f32x4 st[4] = {};
#pragma unroll
    for (int ds = 0; ds < 2; ds++)
#pragma unroll
      for (int ni = 0; ni < 4; ni++)
        st[ni] = mfma16(kf[ds][ni], qf[ds], st[ni]);

    // lane-local softmax over this lane's 16 kv values + 2 shfl_xor
    float tm = -1e30f;
#pragma unroll
    for (int ni = 0; ni < 4; ni++) {
      float a = fmaxf(fmaxf(st[ni][0], st[ni][1]), fmaxf(st[ni][2], st[ni][3]));
      tm = fmaxf(tm, a);
    }
    tm = fmaxf(tm, __shfl_xor(tm, 16));
    tm = fmaxf(tm, __shfl_xor(tm, 32));
    float mnew = fmaxf(m_sm, tm);

    float p[4][4];
    float psum = 0.f;
#pragma unroll
    for (int ni = 0; ni < 4; ni++)
#pragma unroll
      for (int r = 0; r < 4; r++) {
        float e = __expf(st[ni][r] - mnew);
        p[ni][r] = e;
        psum += e;
      }
    psum += __shfl_xor(psum, 16);
    psum += __shfl_xor(psum, 32);
    l_sm = l_sm * __expf(m_sm - mnew) + psum;
    m_sm = mnew;

    // redistribute new max to oacc-row layout; rescale oacc
#pragma unroll
    for (int r = 0; r < 4; r++) {
      float mn = __shfl(mnew, 4 * lg + r);  // lane 4*lg+r owns row 4*lg+r
      float corr = __expf(m_acc[r] - mn);
      m_acc[r] = mn;
#pragma unroll
      for (int ni = 0; ni < 4; ni++) oacc[ni][r] *= corr;
    }

    // P -> LDS (bf16, packed 8B stores, swizzled); wave-private rows
    {
      int sp = swz(myq);
      int base = myq * 64 + (lg & 1) * 4;
#pragma unroll
      for (int ni = 0; ni < 4; ni++) {
        unsigned lo = (unsigned)f2bf(p[ni][0]) | ((unsigned)f2bf(p[ni][1]) << 16);
        unsigned hi = (unsigned)f2bf(p[ni][2]) | ((unsigned)f2bf(p[ni][3]) << 16);
        uint2 pk; pk.x = lo; pk.y = hi;
        int c = ni * 2 + (lg >> 1);
        int pos = (c ^ sp) & 7;
        *reinterpret_cast<uint2*>(&p_lds[base + pos * 8]) = pk;
      }
    }

    // O += P @ V  (pa: wave-private p_lds rows; vb: staged V^T)
#pragma unroll
    for (int ks = 0; ks < 2; ks++) {
      bf16x8 pa, vb[4];
      {
        int pos = ((ks * 4 + lg) ^ swz(myq)) & 7;
        pa = *reinterpret_cast<const bf16x8*>(&p_lds[myq * 64 + pos * 8]);
      }
#pragma unroll
      for (int ni = 0; ni < 4; ni++) {
        int d = ni * 16 + l16;
        int pos = ((ks * 4 + lg) ^ swz(d)) & 7;
        vb[ni] = *reinterpret_cast<const bf16x8*>(&vt_lds[cur][d * 64 + pos * 8]);
      }
#pragma unroll
      for (int ni = 0; ni < 4; ni++)
        oacc[ni] = mfma16(pa, vb[ni], oacc[ni]);
    }

    if (kt < 15) write_v(nxt);
    __syncthreads();
  }

  // epilogue: divide by row-sum (redistributed to oacc-row layout) and store
#pragma unroll
  for (int r = 0; r < 4; r++) {
    float lr = __shfl(l_sm, 4 * lg + r);
    float inv = 1.f / lr;
    int grow = tb + w * 16 + 4 * lg + r;
#pragma unroll
    for (int ni = 0; ni < 4; ni++) {
      int gcol = h * HD + ni * 16 + l16;
      O[(size_t)grow * CDIM + gcol] = f2bf(oacc[ni][r] * inv);
    }
  }
}

extern "C" void kernel_launch(void* const* d_in, const int* in_sizes, int n_in,
                              void* d_out, int out_size, void* d_ws, size_t ws_size,
                              hipStream_t stream) {
  const float* x     = (const float*)d_in[0];
  const float* pos   = (const float*)d_in[1];
  const float* gamma = (const float*)d_in[2];
  const float* beta  = (const float*)d_in[3];
  const float* Wq    = (const float*)d_in[4];
  const float* bq    = (const float*)d_in[5];
  const float* Wk    = (const float*)d_in[6];
  const float* bk    = (const float*)d_in[7];
  const float* Wv    = (const float*)d_in[8];
  const float* bv    = (const float*)d_in[9];
  const float* Wo    = (const float*)d_in[10];
  const float* bo    = (const float*)d_in[11];
  float* out = (float*)d_out;

  ushort_t* xn   = (ushort_t*)d_ws;                    // 8192*768
  ushort_t* wt   = xn + (size_t)TOK * CDIM;            // 3072*768 (q,k,v,o transposed)
  ushort_t* qkv  = wt + (size_t)3072 * CDIM;           // 8192*2304
  ushort_t* aout = qkv + (size_t)TOK * QKV_N;          // 8192*768

  ln_kernel<<<TOK, 256, 0, stream>>>(x, gamma, beta, xn);
  wtrans_kernel<<<dim3(24, 24, 4), dim3(32, 8), 0, stream>>>(Wq, Wk, Wv, Wo, wt);
  gemm_kernel<0><<<dim3(18, 64), 256, 0, stream>>>(xn, wt, bq, bk, bv, pos, qkv);
  attn_kernel<<<dim3(16, NH, 8), 256, 0, stream>>>(qkv, aout);
  gemm_kernel<1><<<dim3(6, 64), 256, 0, stream>>>(aout, wt + (size_t)QKV_N * CDIM,
                                                  bo, nullptr, nullptr, x, out);
}

// Round 5
// 232.840 us; speedup vs baseline: 1.2530x; 1.0221x over previous
//
#include <hip/hip_runtime.h>
#include <hip/hip_bf16.h>

#define TOK 8192
#define CDIM 768
#define NH 12
#define HD 64
#define QKV_N 2304

typedef __attribute__((ext_vector_type(8))) short bf16x8;
typedef __attribute__((ext_vector_type(4))) float f32x4;
typedef unsigned short ushort_t;

__device__ __forceinline__ ushort_t f2bf(float f) {
  unsigned u = __float_as_uint(f);
  u += 0x7fffu + ((u >> 16) & 1u);
  return (ushort_t)(u >> 16);
}

__device__ __forceinline__ f32x4 mfma16(bf16x8 a, bf16x8 b, f32x4 c) {
  return __builtin_amdgcn_mfma_f32_16x16x32_bf16(a, b, c, 0, 0, 0);
}

// XOR swizzle for 64-col (8-chunk) bf16 LDS rows
__device__ __forceinline__ int swz(int r) { return (r ^ (r >> 3)) & 7; }

__device__ __forceinline__ void gload16(const void* g, void* l) {
  __builtin_amdgcn_global_load_lds(
      (const __attribute__((address_space(1))) unsigned int*)g,
      (__attribute__((address_space(3))) unsigned int*)l, 16, 0, 0);
}

// ---------------- LayerNorm: 1 block per token, fp32 stats, bf16 out ----------
__global__ __launch_bounds__(256) void ln_kernel(const float* __restrict__ x,
                                                 const float* __restrict__ gamma,
                                                 const float* __restrict__ beta,
                                                 ushort_t* __restrict__ xn) {
  int t = blockIdx.x;
  const float* row = x + (size_t)t * CDIM;
  float v[3];
  float s = 0.f, s2 = 0.f;
#pragma unroll
  for (int i = 0; i < 3; i++) {
    v[i] = row[threadIdx.x + 256 * i];
    s += v[i];
    s2 += v[i] * v[i];
  }
#pragma unroll
  for (int off = 32; off; off >>= 1) {
    s += __shfl_xor(s, off);
    s2 += __shfl_xor(s2, off);
  }
  __shared__ float red[8];
  int wid = threadIdx.x >> 6, lane = threadIdx.x & 63;
  if (lane == 0) { red[wid] = s; red[wid + 4] = s2; }
  __syncthreads();
  s = red[0] + red[1] + red[2] + red[3];
  s2 = red[4] + red[5] + red[6] + red[7];
  float mu = s * (1.f / CDIM);
  float var = s2 * (1.f / CDIM) - mu * mu;
  float rstd = rsqrtf(var + 1e-5f);
  ushort_t* orow = xn + (size_t)t * CDIM;
#pragma unroll
  for (int i = 0; i < 3; i++) {
    int c = threadIdx.x + 256 * i;
    orow[c] = f2bf((v[i] - mu) * rstd * gamma[c] + beta[c]);
  }
}

// -------- Weight transpose to bf16: wt[z][n][k] = W_z[k][n] ------------------
__global__ __launch_bounds__(256) void wtrans_kernel(const float* __restrict__ Wq,
                                                     const float* __restrict__ Wk,
                                                     const float* __restrict__ Wv,
                                                     const float* __restrict__ Wo,
                                                     ushort_t* __restrict__ wt) {
  const float* W = (blockIdx.z == 0) ? Wq : (blockIdx.z == 1) ? Wk
                   : (blockIdx.z == 2) ? Wv : Wo;
  __shared__ float tile[32][33];
  int tr = blockIdx.y, tc = blockIdx.x;
  int tx = threadIdx.x, ty = threadIdx.y;
#pragma unroll
  for (int j = 0; j < 4; j++) {
    int k = tr * 32 + ty + j * 8;
    tile[ty + j * 8][tx] = W[(size_t)k * CDIM + tc * 32 + tx];
  }
  __syncthreads();
  ushort_t* o = wt + (size_t)blockIdx.z * CDIM * CDIM;
#pragma unroll
  for (int j = 0; j < 4; j++) {
    int n = tc * 32 + ty + j * 8;
    o[(size_t)n * CDIM + tr * 32 + tx] = f2bf(tile[tx][ty + j * 8]);
  }
}

// -------- GEMM (m97 structure): C[m][n] = sum_k A[m][k]*Bt[n][k] + epilogue --
// MODE 0: QKV fused (N=2304), bf16 out; Q third gets (+bias+pos)*0.125
// MODE 1: out-proj (N=768), fp32 out, +bias +fp32 residual
template <int MODE>
__global__ __launch_bounds__(256) void gemm_kernel(
    const ushort_t* __restrict__ A, const ushort_t* __restrict__ Bt,
    const float* __restrict__ b0, const float* __restrict__ b1,
    const float* __restrict__ b2, const float* __restrict__ extra,
    void* __restrict__ outp) {
  __shared__ __align__(16) ushort_t lds_a[128 * 64];
  __shared__ __align__(16) ushort_t lds_b[128 * 64];
  const int NB = (MODE == 0) ? 18 : 6;
  // XCD-chunked swizzle (nwg % 8 == 0 in both modes)
  int lin = blockIdx.y * NB + blockIdx.x;
  int nl = (lin & 7) * (NB * 8) + (lin >> 3);
  const int bn = nl % NB, bm = nl / NB;

  const int tid = threadIdx.x;
  const int lane = tid & 63, wid = tid >> 6;
  const int wr = wid >> 1, wc = wid & 1;
  const int l16 = lane & 15, lg = lane >> 4;
  f32x4 acc[4][4] = {};

  for (int k0 = 0; k0 < CDIM; k0 += 64) {
#pragma unroll
    for (int i = 0; i < 4; i++) {
      int slot = i * 256 + tid;           // 1024 chunks of 16B per tile
      int row = slot >> 3, c8 = (slot & 7) * 8;
      gload16(&A[(size_t)(bm * 128 + row) * CDIM + k0 + c8], &lds_a[slot * 8]);
      gload16(&Bt[(size_t)(bn * 128 + row) * CDIM + k0 + c8], &lds_b[slot * 8]);
    }
    __syncthreads();  // drains vmcnt: staged data visible
#pragma unroll
    for (int kk = 0; kk < 2; kk++) {
      bf16x8 af[4], bfr[4];
#pragma unroll
      for (int mi = 0; mi < 4; mi++)
        af[mi] = *reinterpret_cast<const bf16x8*>(
            &lds_a[(wr * 64 + mi * 16 + l16) * 64 + kk * 32 + lg * 8]);
#pragma unroll
      for (int ni = 0; ni < 4; ni++)
        bfr[ni] = *reinterpret_cast<const bf16x8*>(
            &lds_b[(wc * 64 + ni * 16 + l16) * 64 + kk * 32 + lg * 8]);
#pragma unroll
      for (int mi = 0; mi < 4; mi++)
#pragma unroll
        for (int ni = 0; ni < 4; ni++)
          acc[mi][ni] = mfma16(af[mi], bfr[ni], acc[mi][ni]);
    }
    __syncthreads();  // all reads done before next stage overwrites
  }

#pragma unroll
  for (int mi = 0; mi < 4; mi++)
#pragma unroll
    for (int ni = 0; ni < 4; ni++)
#pragma unroll
      for (int r = 0; r < 4; r++) {
        int grow = bm * 128 + wr * 64 + mi * 16 + 4 * lg + r;
        int gcol = bn * 128 + wc * 64 + ni * 16 + l16;
        float v = acc[mi][ni][r];
        if (MODE == 0) {
          if (gcol < 768) {
            // Q: add bias + pos_embed, pre-scale by 1/sqrt(64) (exact in bf16)
            v = (v + b0[gcol] + extra[(size_t)grow * CDIM + gcol]) * 0.125f;
          } else if (gcol < 1536) {
            v += b1[gcol - 768];
          } else {
            v += b2[gcol - 1536];
          }
          ((ushort_t*)outp)[(size_t)grow * QKV_N + gcol] = f2bf(v);
        } else {
          v += b0[gcol] + extra[(size_t)grow * CDIM + gcol];
          ((float*)outp)[(size_t)grow * CDIM + gcol] = v;
        }
      }
}

// -------- Flash attention v5 ------------------------------------------------
// Same math/layout as v4 (bit-identical output). Changes: hoisted LDS offsets,
// paired-kv vectorized V staging (8 conflict-free dword stores), K register
// prefetch issued after QK^T, raw s_barrier with lgkm-only drain (K/V global
// loads stay in flight across the barrier), setprio around MFMA clusters,
// exact rescale-skip (skips multiply-by-1.0 rescales only).
__global__ __launch_bounds__(256, 4) void attn_kernel(const ushort_t* __restrict__ QKV,
                                                      ushort_t* __restrict__ O) {
  // XCD-chunked swizzle over 1536 = 8 x 192: each XCD owns one batch b
  int lin = (blockIdx.z * NH + blockIdx.y) * 16 + blockIdx.x;
  int nl = (lin & 7) * 192 + (lin >> 3);
  const int qt = nl & 15;
  const int h = (nl >> 4) % NH;
  const int b = nl / 192;

  const int tid = threadIdx.x, lane = tid & 63, w = tid >> 6;
  const int l16 = lane & 15, lg = lane >> 4;
  const int tb = b * 1024 + qt * 64;
  const int co_q = h * HD, co_k = CDIM + h * HD, co_v = 2 * CDIM + h * HD;

  __shared__ __align__(16) ushort_t vt_lds[2][64 * 64];
  __shared__ __align__(16) ushort_t p_lds[64 * 64];

  // Q as B-fragment: rows q = w*16 + l16 (scale 1/8 folded in by QKV-GEMM)
  bf16x8 qf[2];
#pragma unroll
  for (int ds = 0; ds < 2; ds++)
    qf[ds] = *reinterpret_cast<const bf16x8*>(
        &QKV[(size_t)(tb + w * 16 + l16) * QKV_N + co_q + ds * 32 + 8 * lg]);

  const int myq = w * 16 + l16;  // this lane's softmax row (block-local)
  const int sq = swz(myq);
  float m_sm = -1e30f, l_sm = 0.f;  // per-lane row stats (row = myq)
  float m_acc[4];                    // same stats in oacc-row layout (4*lg+r)
#pragma unroll
  for (int r = 0; r < 4; r++) m_acc[r] = -1e30f;
  f32x4 oacc[4] = {};

  // ---- hoisted LDS offsets (loop-invariant) ----
  int poff[4];
#pragma unroll
  for (int ni = 0; ni < 4; ni++)
    poff[ni] = myq * 64 + (lg & 1) * 4 + (((ni * 2 + (lg >> 1)) ^ sq) & 7) * 8;
  int paoff[2];
#pragma unroll
  for (int ks = 0; ks < 2; ks++)
    paoff[ks] = myq * 64 + (((ks * 4 + lg) ^ sq) & 7) * 8;
  int vboff[2][4];
#pragma unroll
  for (int ks = 0; ks < 2; ks++)
#pragma unroll
    for (int ni = 0; ni < 4; ni++) {
      int d = ni * 16 + l16;
      vboff[ks][ni] = d * 64 + (((ks * 4 + lg) ^ swz(d)) & 7) * 8;
    }

  // ---- paired-kv V staging: thread owns rows (kv0, kv0+1), d-chunk d0..d0+7
  const int kv0 = (tid >> 3) * 2, d0 = (tid & 7) * 8;
  const int sV = ((kv0 >> 3) ^ (d0 >> 3)) & 7;
  int voff[8];
#pragma unroll
  for (int u = 0; u < 8; u++)
    voff[u] = (d0 + u) * 64 + ((sV ^ u) & 7) * 8 + (kv0 & 7);
  const ushort_t* vsrc = QKV + (size_t)(b * 1024 + kv0) * QKV_N + co_v + d0;

  uint4 vr0, vr1;
  auto load_v = [&](int kt) {
    vr0 = *reinterpret_cast<const uint4*>(vsrc + (size_t)kt * 64 * QKV_N);
    vr1 = *reinterpret_cast<const uint4*>(vsrc + (size_t)kt * 64 * QKV_N + QKV_N);
  };
  auto write_v = [&](int buf) {
    const unsigned* w0 = reinterpret_cast<const unsigned*>(&vr0);
    const unsigned* w1 = reinterpret_cast<const unsigned*>(&vr1);
#pragma unroll
    for (int u = 0; u < 8; u++) {
      unsigned a = w0[u >> 1], c = w1[u >> 1];
      unsigned val = (u & 1) ? ((a >> 16) | (c & 0xffff0000u))
                             : ((a & 0xffffu) | (c << 16));
      *reinterpret_cast<unsigned*>(&vt_lds[buf][voff[u]]) = val;
    }
  };

  // ---- K fragments: direct from global (L2-hot), prefetched one tile ahead
  const ushort_t* kbase = QKV + (size_t)(b * 1024 + l16) * QKV_N + co_k + 8 * lg;
  bf16x8 kf[2][4];
  auto load_k = [&](int kt) {
#pragma unroll
    for (int ds = 0; ds < 2; ds++)
#pragma unroll
      for (int ni = 0; ni < 4; ni++)
        kf[ds][ni] = *reinterpret_cast<const bf16x8*>(
            kbase + ((size_t)kt * 64 + ni * 16) * QKV_N + ds * 32);
  };

  // prologue
  load_k(0);
  load_v(0);
  write_v(0);
  asm volatile("s_waitcnt lgkmcnt(0)" ::: "memory");
  __builtin_amdgcn_s_barrier();
  __builtin_amdgcn_sched_barrier(0);

  for (int kt = 0; kt < 16; kt++) {
    const int cur = kt & 1, nxt = cur ^ 1;
    if (kt < 15) load_v(kt + 1);  // issue early; consumed by write_v below

    // S^T = K Q^T : lane holds col q=l16, rows kv = ni*16 + 4*lg + r
    f32x4 st[4] = {};
    __builtin_amdgcn_s_setprio(1);
#pragma unroll
    for (int ds = 0; ds < 2; ds++)
#pragma unroll
      for (int ni = 0; ni < 4; ni++)
        st[ni] = mfma16(kf[ds][ni], qf[ds], st[ni]);
    __builtin_amdgcn_s_setprio(0);

    if (kt < 15) load_k(kt + 1);  // prefetch next K; latency hidden below

    // lane-local softmax over this lane's 16 kv values + 2 shfl_xor
    float tm = -1e30f;
#pragma unroll
    for (int ni = 0; ni < 4; ni++) {
      float a = fmaxf(fmaxf(st[ni][0], st[ni][1]), fmaxf(st[ni][2], st[ni][3]));
      tm = fmaxf(tm, a);
    }
    tm = fmaxf(tm, __shfl_xor(tm, 16));
    tm = fmaxf(tm, __shfl_xor(tm, 32));
    float mnew = fmaxf(m_sm, tm);
    bool grew = tm > m_sm;

    float psum = 0.f;
#pragma unroll
    for (int ni = 0; ni < 4; ni++)
#pragma unroll
      for (int r = 0; r < 4; r++) {
        float e = __expf(st[ni][r] - mnew);
        st[ni][r] = e;
        psum += e;
      }
    psum += __shfl_xor(psum, 16);
    psum += __shfl_xor(psum, 32);
    l_sm = l_sm * (grew ? __expf(m_sm - mnew) : 1.0f) + psum;
    m_sm = mnew;

    // redistribute new max to oacc-row layout; rescale oacc (skip if no-op)
    if (__any(grew)) {
#pragma unroll
      for (int r = 0; r < 4; r++) {
        float mn = __shfl(mnew, 4 * lg + r);  // lane 4*lg+r owns row 4*lg+r
        float corr = __expf(m_acc[r] - mn);
        m_acc[r] = mn;
#pragma unroll
        for (int ni = 0; ni < 4; ni++) oacc[ni][r] *= corr;
      }
    }

    // P -> LDS (bf16, packed 8B stores, swizzled); wave-private rows
#pragma unroll
    for (int ni = 0; ni < 4; ni++) {
      unsigned lo = (unsigned)f2bf(st[ni][0]) | ((unsigned)f2bf(st[ni][1]) << 16);
      unsigned hi = (unsigned)f2bf(st[ni][2]) | ((unsigned)f2bf(st[ni][3]) << 16);
      uint2 pk; pk.x = lo; pk.y = hi;
      *reinterpret_cast<uint2*>(&p_lds[poff[ni]]) = pk;
    }

    // O += P @ V  (pa: wave-private p_lds rows; vb: staged V^T)
#pragma unroll
    for (int ks = 0; ks < 2; ks++) {
      bf16x8 pa = *reinterpret_cast<const bf16x8*>(&p_lds[paoff[ks]]);
      bf16x8 vb[4];
#pragma unroll
      for (int ni = 0; ni < 4; ni++)
        vb[ni] = *reinterpret_cast<const bf16x8*>(
            &vt_lds[cur][vboff[ks][ni]]);
      __builtin_amdgcn_s_setprio(1);
#pragma unroll
      for (int ni = 0; ni < 4; ni++)
        oacc[ni] = mfma16(pa, vb[ni], oacc[ni]);
      __builtin_amdgcn_s_setprio(0);
    }

    if (kt < 15) write_v(nxt);  // waits vmcnt for load_v data only
    asm volatile("s_waitcnt lgkmcnt(0)" ::: "memory");
    __builtin_amdgcn_s_barrier();
    __builtin_amdgcn_sched_barrier(0);
  }

  // epilogue: divide by row-sum (redistributed to oacc-row layout) and store
#pragma unroll
  for (int r = 0; r < 4; r++) {
    float lr = __shfl(l_sm, 4 * lg + r);
    float inv = 1.f / lr;
    int grow = tb + w * 16 + 4 * lg + r;
#pragma unroll
    for (int ni = 0; ni < 4; ni++) {
      int gcol = h * HD + ni * 16 + l16;
      O[(size_t)grow * CDIM + gcol] = f2bf(oacc[ni][r] * inv);
    }
  }
}

extern "C" void kernel_launch(void* const* d_in, const int* in_sizes, int n_in,
                              void* d_out, int out_size, void* d_ws, size_t ws_size,
                              hipStream_t stream) {
  const float* x     = (const float*)d_in[0];
  const float* pos   = (const float*)d_in[1];
  const float* gamma = (const float*)d_in[2];
  const float* beta  = (const float*)d_in[3];
  const float* Wq    = (const float*)d_in[4];
  const float* bq    = (const float*)d_in[5];
  const float* Wk    = (const float*)d_in[6];
  const float* bk    = (const float*)d_in[7];
  const float* Wv    = (const float*)d_in[8];
  const float* bv    = (const float*)d_in[9];
  const float* Wo    = (const float*)d_in[10];
  const float* bo    = (const float*)d_in[11];
  float* out = (float*)d_out;

  ushort_t* xn   = (ushort_t*)d_ws;                    // 8192*768
  ushort_t* wt   = xn + (size_t)TOK * CDIM;            // 3072*768 (q,k,v,o transposed)
  ushort_t* qkv  = wt + (size_t)3072 * CDIM;           // 8192*2304
  ushort_t* aout = qkv + (size_t)TOK * QKV_N;          // 8192*768

  ln_kernel<<<TOK, 256, 0, stream>>>(x, gamma, beta, xn);
  wtrans_kernel<<<dim3(24, 24, 4), dim3(32, 8), 0, stream>>>(Wq, Wk, Wv, Wo, wt);
  gemm_kernel<0><<<dim3(18, 64), 256, 0, stream>>>(xn, wt, bq, bk, bv, pos, qkv);
  attn_kernel<<<dim3(16, NH, 8), 256, 0, stream>>>(qkv, aout);
  gemm_kernel<1><<<dim3(6, 64), 256, 0, stream>>>(aout, wt + (size_t)QKV_N * CDIM,
                                                  bo, nullptr, nullptr, x, out);
}

// Round 6
// 221.683 us; speedup vs baseline: 1.3161x; 1.0503x over previous
//
#include <hip/hip_runtime.h>
#include <hip/hip_bf16.h>

#define TOK 8192
#define CDIM 768
#define NH 12
#define HD 64
#define QKV_N 2304

typedef __attribute__((ext_vector_type(8))) short bf16x8;
typedef __attribute__((ext_vector_type(4))) float f32x4;
typedef unsigned short ushort_t;

__device__ __forceinline__ ushort_t f2bf(float f) {
  unsigned u = __float_as_uint(f);
  u += 0x7fffu + ((u >> 16) & 1u);
  return (ushort_t)(u >> 16);
}

__device__ __forceinline__ f32x4 mfma16(bf16x8 a, bf16x8 b, f32x4 c) {
  return __builtin_amdgcn_mfma_f32_16x16x32_bf16(a, b, c, 0, 0, 0);
}

// XOR swizzle for 64-col (8-chunk) bf16 LDS rows
__device__ __forceinline__ int swz(int r) { return (r ^ (r >> 3)) & 7; }

__device__ __forceinline__ void gload16(const void* g, void* l) {
  __builtin_amdgcn_global_load_lds(
      (const __attribute__((address_space(1))) unsigned int*)g,
      (__attribute__((address_space(3))) unsigned int*)l, 16, 0, 0);
}

// ---------------- LayerNorm: 1 block per token, fp32 stats, bf16 out ----------
__global__ __launch_bounds__(256) void ln_kernel(const float* __restrict__ x,
                                                 const float* __restrict__ gamma,
                                                 const float* __restrict__ beta,
                                                 ushort_t* __restrict__ xn) {
  int t = blockIdx.x;
  const float* row = x + (size_t)t * CDIM;
  float v[3];
  float s = 0.f, s2 = 0.f;
#pragma unroll
  for (int i = 0; i < 3; i++) {
    v[i] = row[threadIdx.x + 256 * i];
    s += v[i];
    s2 += v[i] * v[i];
  }
#pragma unroll
  for (int off = 32; off; off >>= 1) {
    s += __shfl_xor(s, off);
    s2 += __shfl_xor(s2, off);
  }
  __shared__ float red[8];
  int wid = threadIdx.x >> 6, lane = threadIdx.x & 63;
  if (lane == 0) { red[wid] = s; red[wid + 4] = s2; }
  __syncthreads();
  s = red[0] + red[1] + red[2] + red[3];
  s2 = red[4] + red[5] + red[6] + red[7];
  float mu = s * (1.f / CDIM);
  float var = s2 * (1.f / CDIM) - mu * mu;
  float rstd = rsqrtf(var + 1e-5f);
  ushort_t* orow = xn + (size_t)t * CDIM;
#pragma unroll
  for (int i = 0; i < 3; i++) {
    int c = threadIdx.x + 256 * i;
    orow[c] = f2bf((v[i] - mu) * rstd * gamma[c] + beta[c]);
  }
}

// -------- Weight transpose to bf16: wt[z][n][k] = W_z[k][n] ------------------
__global__ __launch_bounds__(256) void wtrans_kernel(const float* __restrict__ Wq,
                                                     const float* __restrict__ Wk,
                                                     const float* __restrict__ Wv,
                                                     const float* __restrict__ Wo,
                                                     ushort_t* __restrict__ wt) {
  const float* W = (blockIdx.z == 0) ? Wq : (blockIdx.z == 1) ? Wk
                   : (blockIdx.z == 2) ? Wv : Wo;
  __shared__ float tile[32][33];
  int tr = blockIdx.y, tc = blockIdx.x;
  int tx = threadIdx.x, ty = threadIdx.y;
#pragma unroll
  for (int j = 0; j < 4; j++) {
    int k = tr * 32 + ty + j * 8;
    tile[ty + j * 8][tx] = W[(size_t)k * CDIM + tc * 32 + tx];
  }
  __syncthreads();
  ushort_t* o = wt + (size_t)blockIdx.z * CDIM * CDIM;
#pragma unroll
  for (int j = 0; j < 4; j++) {
    int n = tc * 32 + ty + j * 8;
    o[(size_t)n * CDIM + tr * 32 + tx] = f2bf(tile[tx][ty + j * 8]);
  }
}

// -------- GEMM (m97 structure + T2 swizzle): C = A Bt^T + epilogue -----------
// LDS: linear gload16 dest, pre-swizzled SOURCE column, swizzled ds_read
// (same proven pattern as attn k_lds) -> conflict-free b128 fragment reads.
// MODE 0: QKV fused (N=2304), bf16 out; Q third gets (+bias+pos)*0.125
// MODE 1: out-proj (N=768), fp32 out, +bias +fp32 residual
template <int MODE>
__global__ __launch_bounds__(256) void gemm_kernel(
    const ushort_t* __restrict__ A, const ushort_t* __restrict__ Bt,
    const float* __restrict__ b0, const float* __restrict__ b1,
    const float* __restrict__ b2, const float* __restrict__ extra,
    void* __restrict__ outp) {
  __shared__ __align__(16) ushort_t lds_a[128 * 64];
  __shared__ __align__(16) ushort_t lds_b[128 * 64];
  const int NB = (MODE == 0) ? 18 : 6;
  // XCD-chunked swizzle (nwg % 8 == 0 in both modes)
  int lin = blockIdx.y * NB + blockIdx.x;
  int nl = (lin & 7) * (NB * 8) + (lin >> 3);
  const int bn = nl % NB, bm = nl / NB;

  const int tid = threadIdx.x;
  const int lane = tid & 63, wid = tid >> 6;
  const int wr = wid >> 1, wc = wid & 1;
  const int l16 = lane & 15, lg = lane >> 4;
  f32x4 acc[4][4] = {};

  // hoisted swizzled read offsets (loop-invariant except kk -> 2 variants)
  int aoff[2][4], boff[2][4];
#pragma unroll
  for (int kk = 0; kk < 2; kk++) {
#pragma unroll
    for (int mi = 0; mi < 4; mi++) {
      int r = wr * 64 + mi * 16 + l16;
      aoff[kk][mi] = r * 64 + (((kk * 4 + lg) ^ swz(r)) & 7) * 8;
    }
#pragma unroll
    for (int ni = 0; ni < 4; ni++) {
      int r = wc * 64 + ni * 16 + l16;
      boff[kk][ni] = r * 64 + (((kk * 4 + lg) ^ swz(r)) & 7) * 8;
    }
  }

  for (int k0 = 0; k0 < CDIM; k0 += 64) {
#pragma unroll
    for (int i = 0; i < 4; i++) {
      int slot = i * 256 + tid;           // 1024 chunks of 16B per tile
      int row = slot >> 3, j = slot & 7;
      int c8 = ((j ^ swz(row)) & 7) * 8;  // pre-swizzled source column
      gload16(&A[(size_t)(bm * 128 + row) * CDIM + k0 + c8], &lds_a[slot * 8]);
      gload16(&Bt[(size_t)(bn * 128 + row) * CDIM + k0 + c8], &lds_b[slot * 8]);
    }
    __syncthreads();  // drains vmcnt: staged data visible
#pragma unroll
    for (int kk = 0; kk < 2; kk++) {
      bf16x8 af[4], bfr[4];
#pragma unroll
      for (int mi = 0; mi < 4; mi++)
        af[mi] = *reinterpret_cast<const bf16x8*>(&lds_a[aoff[kk][mi]]);
#pragma unroll
      for (int ni = 0; ni < 4; ni++)
        bfr[ni] = *reinterpret_cast<const bf16x8*>(&lds_b[boff[kk][ni]]);
#pragma unroll
      for (int mi = 0; mi < 4; mi++)
#pragma unroll
        for (int ni = 0; ni < 4; ni++)
          acc[mi][ni] = mfma16(af[mi], bfr[ni], acc[mi][ni]);
    }
    __syncthreads();  // all reads done before next stage overwrites
  }

#pragma unroll
  for (int mi = 0; mi < 4; mi++)
#pragma unroll
    for (int ni = 0; ni < 4; ni++)
#pragma unroll
      for (int r = 0; r < 4; r++) {
        int grow = bm * 128 + wr * 64 + mi * 16 + 4 * lg + r;
        int gcol = bn * 128 + wc * 64 + ni * 16 + l16;
        float v = acc[mi][ni][r];
        if (MODE == 0) {
          if (gcol < 768) {
            // Q: add bias + pos_embed, pre-scale by 1/sqrt(64) (exact in bf16)
            v = (v + b0[gcol] + extra[(size_t)grow * CDIM + gcol]) * 0.125f;
          } else if (gcol < 1536) {
            v += b1[gcol - 768];
          } else {
            v += b2[gcol - 1536];
          }
          ((ushort_t*)outp)[(size_t)grow * QKV_N + gcol] = f2bf(v);
        } else {
          v += b0[gcol] + extra[(size_t)grow * CDIM + gcol];
          ((float*)outp)[(size_t)grow * CDIM + gcol] = v;
        }
      }
}

// -------- Flash attention v5 (unchanged from round 5) ------------------------
__global__ __launch_bounds__(256, 4) void attn_kernel(const ushort_t* __restrict__ QKV,
                                                      ushort_t* __restrict__ O) {
  // XCD-chunked swizzle over 1536 = 8 x 192: each XCD owns one batch b
  int lin = (blockIdx.z * NH + blockIdx.y) * 16 + blockIdx.x;
  int nl = (lin & 7) * 192 + (lin >> 3);
  const int qt = nl & 15;
  const int h = (nl >> 4) % NH;
  const int b = nl / 192;

  const int tid = threadIdx.x, lane = tid & 63, w = tid >> 6;
  const int l16 = lane & 15, lg = lane >> 4;
  const int tb = b * 1024 + qt * 64;
  const int co_q = h * HD, co_k = CDIM + h * HD, co_v = 2 * CDIM + h * HD;

  __shared__ __align__(16) ushort_t vt_lds[2][64 * 64];
  __shared__ __align__(16) ushort_t p_lds[64 * 64];

  // Q as B-fragment: rows q = w*16 + l16 (scale 1/8 folded in by QKV-GEMM)
  bf16x8 qf[2];
#pragma unroll
  for (int ds = 0; ds < 2; ds++)
    qf[ds] = *reinterpret_cast<const bf16x8*>(
        &QKV[(size_t)(tb + w * 16 + l16) * QKV_N + co_q + ds * 32 + 8 * lg]);

  const int myq = w * 16 + l16;  // this lane's softmax row (block-local)
  const int sq = swz(myq);
  float m_sm = -1e30f, l_sm = 0.f;  // per-lane row stats (row = myq)
  float m_acc[4];                    // same stats in oacc-row layout (4*lg+r)
#pragma unroll
  for (int r = 0; r < 4; r++) m_acc[r] = -1e30f;
  f32x4 oacc[4] = {};

  // ---- hoisted LDS offsets (loop-invariant) ----
  int poff[4];
#pragma unroll
  for (int ni = 0; ni < 4; ni++)
    poff[ni] = myq * 64 + (lg & 1) * 4 + (((ni * 2 + (lg >> 1)) ^ sq) & 7) * 8;
  int paoff[2];
#pragma unroll
  for (int ks = 0; ks < 2; ks++)
    paoff[ks] = myq * 64 + (((ks * 4 + lg) ^ sq) & 7) * 8;
  int vboff[2][4];
#pragma unroll
  for (int ks = 0; ks < 2; ks++)
#pragma unroll
    for (int ni = 0; ni < 4; ni++) {
      int d = ni * 16 + l16;
      vboff[ks][ni] = d * 64 + (((ks * 4 + lg) ^ swz(d)) & 7) * 8;
    }

  // ---- paired-kv V staging: thread owns rows (kv0, kv0+1), d-chunk d0..d0+7
  const int kv0 = (tid >> 3) * 2, d0 = (tid & 7) * 8;
  const int sV = ((kv0 >> 3) ^ (d0 >> 3)) & 7;
  int voff[8];
#pragma unroll
  for (int u = 0; u < 8; u++)
    voff[u] = (d0 + u) * 64 + ((sV ^ u) & 7) * 8 + (kv0 & 7);
  const ushort_t* vsrc = QKV + (size_t)(b * 1024 + kv0) * QKV_N + co_v + d0;

  uint4 vr0, vr1;
  auto load_v = [&](int kt) {
    vr0 = *reinterpret_cast<const uint4*>(vsrc + (size_t)kt * 64 * QKV_N);
    vr1 = *reinterpret_cast<const uint4*>(vsrc + (size_t)kt * 64 * QKV_N + QKV_N);
  };
  auto write_v = [&](int buf) {
    const unsigned* w0 = reinterpret_cast<const unsigned*>(&vr0);
    const unsigned* w1 = reinterpret_cast<const unsigned*>(&vr1);
#pragma unroll
    for (int u = 0; u < 8; u++) {
      unsigned a = w0[u >> 1], c = w1[u >> 1];
      unsigned val = (u & 1) ? ((a >> 16) | (c & 0xffff0000u))
                             : ((a & 0xffffu) | (c << 16));
      *reinterpret_cast<unsigned*>(&vt_lds[buf][voff[u]]) = val;
    }
  };

  // ---- K fragments: direct from global (L2-hot), prefetched one tile ahead
  const ushort_t* kbase = QKV + (size_t)(b * 1024 + l16) * QKV_N + co_k + 8 * lg;
  bf16x8 kf[2][4];
  auto load_k = [&](int kt) {
#pragma unroll
    for (int ds = 0; ds < 2; ds++)
#pragma unroll
      for (int ni = 0; ni < 4; ni++)
        kf[ds][ni] = *reinterpret_cast<const bf16x8*>(
            kbase + ((size_t)kt * 64 + ni * 16) * QKV_N + ds * 32);
  };

  // prologue
  load_k(0);
  load_v(0);
  write_v(0);
  asm volatile("s_waitcnt lgkmcnt(0)" ::: "memory");
  __builtin_amdgcn_s_barrier();
  __builtin_amdgcn_sched_barrier(0);

  for (int kt = 0; kt < 16; kt++) {
    const int cur = kt & 1, nxt = cur ^ 1;
    if (kt < 15) load_v(kt + 1);  // issue early; consumed by write_v below

    // S^T = K Q^T : lane holds col q=l16, rows kv = ni*16 + 4*lg + r
    f32x4 st[4] = {};
    __builtin_amdgcn_s_setprio(1);
#pragma unroll
    for (int ds = 0; ds < 2; ds++)
#pragma unroll
      for (int ni = 0; ni < 4; ni++)
        st[ni] = mfma16(kf[ds][ni], qf[ds], st[ni]);
    __builtin_amdgcn_s_setprio(0);

    if (kt < 15) load_k(kt + 1);  // prefetch next K; latency hidden below

    // lane-local softmax over this lane's 16 kv values + 2 shfl_xor
    float tm = -1e30f;
#pragma unroll
    for (int ni = 0; ni < 4; ni++) {
      float a = fmaxf(fmaxf(st[ni][0], st[ni][1]), fmaxf(st[ni][2], st[ni][3]));
      tm = fmaxf(tm, a);
    }
    tm = fmaxf(tm, __shfl_xor(tm, 16));
    tm = fmaxf(tm, __shfl_xor(tm, 32));
    float mnew = fmaxf(m_sm, tm);
    bool grew = tm > m_sm;

    float psum = 0.f;
#pragma unroll
    for (int ni = 0; ni < 4; ni++)
#pragma unroll
      for (int r = 0; r < 4; r++) {
        float e = __expf(st[ni][r] - mnew);
        st[ni][r] = e;
        psum += e;
      }
    psum += __shfl_xor(psum, 16);
    psum += __shfl_xor(psum, 32);
    l_sm = l_sm * (grew ? __expf(m_sm - mnew) : 1.0f) + psum;
    m_sm = mnew;

    // redistribute new max to oacc-row layout; rescale oacc (skip if no-op)
    if (__any(grew)) {
#pragma unroll
      for (int r = 0; r < 4; r++) {
        float mn = __shfl(mnew, 4 * lg + r);  // lane 4*lg+r owns row 4*lg+r
        float corr = __expf(m_acc[r] - mn);
        m_acc[r] = mn;
#pragma unroll
        for (int ni = 0; ni < 4; ni++) oacc[ni][r] *= corr;
      }
    }

    // P -> LDS (bf16, packed 8B stores, swizzled); wave-private rows
#pragma unroll
    for (int ni = 0; ni < 4; ni++) {
      unsigned lo = (unsigned)f2bf(st[ni][0]) | ((unsigned)f2bf(st[ni][1]) << 16);
      unsigned hi = (unsigned)f2bf(st[ni][2]) | ((unsigned)f2bf(st[ni][3]) << 16);
      uint2 pk; pk.x = lo; pk.y = hi;
      *reinterpret_cast<uint2*>(&p_lds[poff[ni]]) = pk;
    }

    // O += P @ V  (pa: wave-private p_lds rows; vb: staged V^T)
#pragma unroll
    for (int ks = 0; ks < 2; ks++) {
      bf16x8 pa = *reinterpret_cast<const bf16x8*>(&p_lds[paoff[ks]]);
      bf16x8 vb[4];
#pragma unroll
      for (int ni = 0; ni < 4; ni++)
        vb[ni] = *reinterpret_cast<const bf16x8*>(
            &vt_lds[cur][vboff[ks][ni]]);
      __builtin_amdgcn_s_setprio(1);
#pragma unroll
      for (int ni = 0; ni < 4; ni++)
        oacc[ni] = mfma16(pa, vb[ni], oacc[ni]);
      __builtin_amdgcn_s_setprio(0);
    }

    if (kt < 15) write_v(nxt);  // waits vmcnt for load_v data only
    asm volatile("s_waitcnt lgkmcnt(0)" ::: "memory");
    __builtin_amdgcn_s_barrier();
    __builtin_amdgcn_sched_barrier(0);
  }

  // epilogue: divide by row-sum (redistributed to oacc-row layout) and store
#pragma unroll
  for (int r = 0; r < 4; r++) {
    float lr = __shfl(l_sm, 4 * lg + r);
    float inv = 1.f / lr;
    int grow = tb + w * 16 + 4 * lg + r;
#pragma unroll
    for (int ni = 0; ni < 4; ni++) {
      int gcol = h * HD + ni * 16 + l16;
      O[(size_t)grow * CDIM + gcol] = f2bf(oacc[ni][r] * inv);
    }
  }
}

extern "C" void kernel_launch(void* const* d_in, const int* in_sizes, int n_in,
                              void* d_out, int out_size, void* d_ws, size_t ws_size,
                              hipStream_t stream) {
  const float* x     = (const float*)d_in[0];
  const float* pos   = (const float*)d_in[1];
  const float* gamma = (const float*)d_in[2];
  const float* beta  = (const float*)d_in[3];
  const float* Wq    = (const float*)d_in[4];
  const float* bq    = (const float*)d_in[5];
  const float* Wk    = (const float*)d_in[6];
  const float* bk    = (const float*)d_in[7];
  const float* Wv    = (const float*)d_in[8];
  const float* bv    = (const float*)d_in[9];
  const float* Wo    = (const float*)d_in[10];
  const float* bo    = (const float*)d_in[11];
  float* out = (float*)d_out;

  ushort_t* xn   = (ushort_t*)d_ws;                    // 8192*768
  ushort_t* wt   = xn + (size_t)TOK * CDIM;            // 3072*768 (q,k,v,o transposed)
  ushort_t* qkv  = wt + (size_t)3072 * CDIM;           // 8192*2304
  ushort_t* aout = qkv + (size_t)TOK * QKV_N;          // 8192*768

  ln_kernel<<<TOK, 256, 0, stream>>>(x, gamma, beta, xn);
  wtrans_kernel<<<dim3(24, 24, 4), dim3(32, 8), 0, stream>>>(Wq, Wk, Wv, Wo, wt);
  gemm_kernel<0><<<dim3(18, 64), 256, 0, stream>>>(xn, wt, bq, bk, bv, pos, qkv);
  attn_kernel<<<dim3(16, NH, 8), 256, 0, stream>>>(qkv, aout);
  gemm_kernel<1><<<dim3(6, 64), 256, 0, stream>>>(aout, wt + (size_t)QKV_N * CDIM,
                                                  bo, nullptr, nullptr, x, out);
}